// Round 1
// baseline (3382.050 us; speedup 1.0000x reference)
//
#include <hip/hip_runtime.h>

#define BB 4
#define TT 2048
#define CC 1024
#define HH 8
#define DD 128
#define KTOT 2160
#define GATE0 2112
#define MQ (BB*TT)
#define MKV (BB*KTOT)

// ---------------- gather KV input rows: [B,2160,1024] = concat(x, h_t, h_a, p) ----------------
__global__ __launch_bounds__(256) void gather_kv(const float* __restrict__ x, const float* __restrict__ ht,
        const float* __restrict__ ha, const float* __restrict__ p, float* __restrict__ kvin) {
    int idx = blockIdx.x * 256 + threadIdx.x;   // one float4 per thread, grid exact
    int col4 = idx & 255;                        // CC/4 = 256
    int row  = idx >> 8;
    int b = row / KTOT, j = row - b * KTOT;
    const float* src;
    if (j < 2048)      src = x  + ((size_t)b*TT + j)*CC;
    else if (j < 2112) src = ht + ((size_t)b*64 + (j-2048))*CC;
    else if (j < 2128) src = ha + ((size_t)b*16 + (j-2112))*CC;
    else               src = p  + ((size_t)b*32 + (j-2128))*CC;
    ((float4*)kvin)[idx] = ((const float4*)src)[col4];
}

// ---------------- generic fp32 GEMM: C[M,1024] = A[M,1024] @ W[1024,1024] + bias (+res / relu) --
// EPI: 0 = none, 1 = add residual, 2 = relu
template<int EPI>
__global__ __launch_bounds__(256) void gemm1024(const float* __restrict__ A, const float* __restrict__ W,
        const float* __restrict__ bias, const float* __restrict__ res, float* __restrict__ Cout, int M) {
    __shared__ float As[16][68];   // [k][row], padded
    __shared__ float Bs[16][68];   // [k][col], padded (16B-aligned rows)
    const int t = threadIdx.x;
    const int row0 = blockIdx.y * 64, col0 = blockIdx.x * 64;
    const int tx = t & 15, ty = t >> 4;
    const int ar = t >> 2, ak4 = t & 3;
    const int br = t >> 4, bc4 = t & 15;
    float acc[4][4] = {};
    const float* Ap = A + (size_t)(row0 + ar)*CC + ak4*4;
    const float* Wp = W + (size_t)br*CC + col0 + bc4*4;
    for (int k0 = 0; k0 < CC; k0 += 16) {
        float4 fa = *(const float4*)(Ap + k0);
        float4 fb = *(const float4*)(Wp + (size_t)k0*CC);
        __syncthreads();
        As[ak4*4+0][ar] = fa.x;
        As[ak4*4+1][ar] = fa.y;
        As[ak4*4+2][ar] = fa.z;
        As[ak4*4+3][ar] = fa.w;
        *(float4*)&Bs[br][bc4*4] = fb;
        __syncthreads();
        #pragma unroll
        for (int kk = 0; kk < 16; kk++) {
            float4 av = *(const float4*)&As[kk][ty*4];
            float4 bv = *(const float4*)&Bs[kk][tx*4];
            float a4[4] = {av.x, av.y, av.z, av.w};
            float b4[4] = {bv.x, bv.y, bv.z, bv.w};
            #pragma unroll
            for (int i = 0; i < 4; i++)
                #pragma unroll
                for (int j = 0; j < 4; j++)
                    acc[i][j] = fmaf(a4[i], b4[j], acc[i][j]);
        }
    }
    float4 b4v = *(const float4*)&bias[col0 + tx*4];
    #pragma unroll
    for (int i = 0; i < 4; i++) {
        int r = row0 + ty*4 + i;
        float4 o;
        o.x = acc[i][0] + b4v.x; o.y = acc[i][1] + b4v.y;
        o.z = acc[i][2] + b4v.z; o.w = acc[i][3] + b4v.w;
        if (EPI == 1) {
            float4 rv = *(const float4*)(res + (size_t)r*CC + col0 + tx*4);
            o.x += rv.x; o.y += rv.y; o.z += rv.z; o.w += rv.w;
        }
        if (EPI == 2) {
            o.x = fmaxf(o.x, 0.f); o.y = fmaxf(o.y, 0.f);
            o.z = fmaxf(o.z, 0.f); o.w = fmaxf(o.w, 0.f);
        }
        *(float4*)(Cout + (size_t)r*CC + col0 + tx*4) = o;
    }
}

// ---------------- flash attention, fp32, QB=64 KB=64 ----------------
__global__ __launch_bounds__(256) void attn_kernel(const float* __restrict__ Q, const float* __restrict__ Kg,
        const float* __restrict__ Vg, const float* __restrict__ gate, float* __restrict__ AO) {
    __shared__ float q_s[64][132];
    __shared__ float k_s[64][132];
    __shared__ float v_s[64][132];   // XOR bank-permuted columns
    __shared__ float s_s[64][68];
    const int qt = blockIdx.x, h = blockIdx.y, b = blockIdx.z;
    const int t = threadIdx.x;
    const int r = t >> 2, c = t & 3;         // row 0..63, col-group 0..3 (cols c*32..c*32+31)
    const int q0 = qt * 64;
    const float ratio = tanhf(gate[0]);
    const float scl = 0.088388347648318447f; // 1/sqrt(128)
    #pragma unroll
    for (int u = 0; u < 8; u++) {
        int f = t + u*256;
        int rr = f >> 5, c4 = f & 31;
        *(float4*)&q_s[rr][c4*4] =
            *(const float4*)(Q + ((size_t)(b*TT + q0 + rr))*CC + h*DD + c4*4);
    }
    float o[32] = {};
    float m = -__builtin_inff(), l = 0.f;
    const size_t kvbase = (size_t)b * KTOT;
    for (int kt = 0; kt < 34; kt++) {
        const int j0 = kt * 64;
        const int nk = (KTOT - j0 < 64) ? (KTOT - j0) : 64;
        __syncthreads();   // protect k_s/v_s from previous iteration's readers
        #pragma unroll
        for (int u = 0; u < 8; u++) {
            int f = t + u*256;
            int rr = f >> 5, c4 = f & 31;
            if (rr < nk) {
                *(float4*)&k_s[rr][c4*4] =
                    *(const float4*)(Kg + (kvbase + j0 + rr)*CC + h*DD + c4*4);
                int d4 = c4*4;
                int phys = d4 ^ ((((unsigned)d4 >> 5) & 3) << 2);
                *(float4*)&v_s[rr][phys] =
                    *(const float4*)(Vg + (kvbase + j0 + rr)*CC + h*DD + c4*4);
            }
        }
        __syncthreads();
        // ---- scores: this thread handles keys jj = c + 4*ji ----
        float sacc[16] = {};
        #pragma unroll
        for (int d4 = 0; d4 < DD; d4 += 4) {
            float4 qv = *(const float4*)&q_s[r][d4];
            #pragma unroll
            for (int ji = 0; ji < 16; ji++) {
                const int jj = c + ji*4;
                float4 kv = *(const float4*)&k_s[jj][d4];
                sacc[ji] = fmaf(qv.x, kv.x, sacc[ji]);
                sacc[ji] = fmaf(qv.y, kv.y, sacc[ji]);
                sacc[ji] = fmaf(qv.z, kv.z, sacc[ji]);
                sacc[ji] = fmaf(qv.w, kv.w, sacc[ji]);
            }
        }
        #pragma unroll
        for (int ji = 0; ji < 16; ji++) {
            const int jj = c + ji*4;
            const int jg = j0 + jj;
            float s;
            if (jg < KTOT) {
                float gm = (jg >= GATE0) ? ratio : 1.0f;
                s = sacc[ji] * gm * scl;
            } else {
                s = -__builtin_inff();
            }
            s_s[r][jj] = s;
        }
        // ---- online softmax (row r owned by lanes 4r..4r+3, same wave: no barrier) ----
        float tmax = m;
        #pragma unroll
        for (int j4 = 0; j4 < 64; j4 += 4) {
            float4 sv = *(const float4*)&s_s[r][j4];
            tmax = fmaxf(tmax, fmaxf(fmaxf(sv.x, sv.y), fmaxf(sv.z, sv.w)));
        }
        const float rescale = __expf(m - tmax);
        m = tmax;
        l *= rescale;
        #pragma unroll
        for (int i = 0; i < 32; i++) o[i] *= rescale;
        float lsum = 0.f;
        #pragma unroll
        for (int jq = 0; jq < 4; jq++) {
            float4 sv = *(const float4*)&s_s[r][c*16 + jq*4];
            float4 pv;
            pv.x = __expf(sv.x - m);
            pv.y = __expf(sv.y - m);
            pv.z = __expf(sv.z - m);
            pv.w = __expf(sv.w - m);
            lsum += pv.x + pv.y + pv.z + pv.w;
            *(float4*)&s_s[r][c*16 + jq*4] = pv;
        }
        lsum += __shfl_xor(lsum, 1);
        lsum += __shfl_xor(lsum, 2);
        l += lsum;
        // ---- accumulate O += P @ V (perm'd v_s reads are bank-conflict-free) ----
        #pragma unroll
        for (int j = 0; j < 64; j++) {
            const float pj = s_s[r][j];
            #pragma unroll
            for (int ii = 0; ii < 8; ii++) {
                const int d4 = c*32 + ii*4;
                const int phys = d4 ^ (c << 2);
                float4 vv = *(const float4*)&v_s[j][phys];
                o[ii*4+0] = fmaf(pj, vv.x, o[ii*4+0]);
                o[ii*4+1] = fmaf(pj, vv.y, o[ii*4+1]);
                o[ii*4+2] = fmaf(pj, vv.z, o[ii*4+2]);
                o[ii*4+3] = fmaf(pj, vv.w, o[ii*4+3]);
            }
        }
    }
    const float invl = 1.0f / l;
    #pragma unroll
    for (int ii = 0; ii < 8; ii++) {
        float4 ov;
        ov.x = o[ii*4+0] * invl;
        ov.y = o[ii*4+1] * invl;
        ov.z = o[ii*4+2] * invl;
        ov.w = o[ii*4+3] * invl;
        *(float4*)(AO + ((size_t)(b*TT + q0 + r))*CC + h*DD + c*32 + ii*4) = ov;
    }
}

// ---------------- LayerNorm over last dim (1024) ----------------
__global__ __launch_bounds__(256) void ln_kernel(const float* __restrict__ Y, const float* __restrict__ g,
        const float* __restrict__ bb, float* __restrict__ Out) {
    const int row = blockIdx.x;
    const int t = threadIdx.x;
    float4 v = ((const float4*)(Y + (size_t)row*CC))[t];
    float s  = v.x + v.y + v.z + v.w;
    float sq = v.x*v.x + v.y*v.y + v.z*v.z + v.w*v.w;
    #pragma unroll
    for (int off = 32; off >= 1; off >>= 1) {
        s  += __shfl_xor(s, off);
        sq += __shfl_xor(sq, off);
    }
    __shared__ float ssum[4], ssq[4];
    const int w = t >> 6;
    if ((t & 63) == 0) { ssum[w] = s; ssq[w] = sq; }
    __syncthreads();
    s  = ssum[0] + ssum[1] + ssum[2] + ssum[3];
    sq = ssq[0]  + ssq[1]  + ssq[2]  + ssq[3];
    const float mu  = s * (1.f/1024.f);
    const float var = sq * (1.f/1024.f) - mu*mu;
    const float inv = rsqrtf(var + 1e-5f);
    float4 g4 = ((const float4*)g)[t];
    float4 b4 = ((const float4*)bb)[t];
    float4 o;
    o.x = (v.x - mu)*inv*g4.x + b4.x;
    o.y = (v.y - mu)*inv*g4.y + b4.y;
    o.z = (v.z - mu)*inv*g4.z + b4.z;
    o.w = (v.w - mu)*inv*g4.w + b4.w;
    ((float4*)(Out + (size_t)row*CC))[t] = o;
}

extern "C" void kernel_launch(void* const* d_in, const int* in_sizes, int n_in,
                              void* d_out, int out_size, void* d_ws, size_t ws_size,
                              hipStream_t stream) {
    const float* x    = (const float*)d_in[0];
    const float* h_t  = (const float*)d_in[1];
    const float* h_a  = (const float*)d_in[2];
    const float* p    = (const float*)d_in[3];
    const float* Wq   = (const float*)d_in[4];
    const float* bq   = (const float*)d_in[5];
    const float* Wk   = (const float*)d_in[6];
    const float* bk   = (const float*)d_in[7];
    const float* Wv   = (const float*)d_in[8];
    const float* bv   = (const float*)d_in[9];
    const float* Wo   = (const float*)d_in[10];
    const float* bo   = (const float*)d_in[11];
    const float* ln_g = (const float*)d_in[12];
    const float* ln_b = (const float*)d_in[13];
    const float* Wf   = (const float*)d_in[14];
    const float* bf   = (const float*)d_in[15];
    const float* gate = (const float*)d_in[16];
    float* out = (float*)d_out;

    float* ws   = (float*)d_ws;
    float* Qb   = ws;                              // MQ*CC
    float* KVin = Qb   + (size_t)MQ*CC;            // MKV*CC
    float* Kb   = KVin + (size_t)MKV*CC;           // MKV*CC
    float* Vb   = Kb   + (size_t)MKV*CC;           // MKV*CC
    float* AO   = Vb   + (size_t)MKV*CC;           // MQ*CC
    float* Y    = KVin;                            // alias: KVin dead after K/V GEMMs
    float* YN   = Qb;                              // alias: Q dead after attention

    gather_kv<<<MKV*CC/4/256, 256, 0, stream>>>(x, h_t, h_a, p, KVin);
    gemm1024<0><<<dim3(16, MQ/64),  256, 0, stream>>>(x,    Wq, bq, nullptr, Qb, MQ);
    gemm1024<0><<<dim3(16, MKV/64), 256, 0, stream>>>(KVin, Wk, bk, nullptr, Kb, MKV);
    gemm1024<0><<<dim3(16, MKV/64), 256, 0, stream>>>(KVin, Wv, bv, nullptr, Vb, MKV);
    attn_kernel<<<dim3(TT/64, HH, BB), 256, 0, stream>>>(Qb, Kb, Vb, gate, AO);
    gemm1024<1><<<dim3(16, MQ/64),  256, 0, stream>>>(AO,   Wo, bo, x, Y, MQ);
    ln_kernel<<<MQ, 256, 0, stream>>>(Y, ln_g, ln_b, YN);
    gemm1024<2><<<dim3(16, MQ/64),  256, 0, stream>>>(YN,   Wf, bf, nullptr, out, MQ);
}

// Round 2
// 2439.277 us; speedup vs baseline: 1.3865x; 1.3865x over previous
//
#include <hip/hip_runtime.h>

#define BB 4
#define TT 2048
#define CC 1024
#define HH 8
#define DD 128
#define KTOT 2160
#define GATE0 2112
#define MQ (BB*TT)
#define MKVP 8704   /* 8640 padded to 68*128 */

typedef __attribute__((ext_vector_type(4))) float f32x4;
typedef __attribute__((ext_vector_type(8))) short bf16x8;

__device__ __forceinline__ unsigned short f2bf(float f) {
    unsigned u = __float_as_uint(f);
    unsigned r = u + 0x7FFFu + ((u >> 16) & 1u);
    return (unsigned short)(r >> 16);
}

__device__ __forceinline__ void async16(const ushort* g, ushort* l) {
    __builtin_amdgcn_global_load_lds((const __attribute__((address_space(1))) void*)g,
                                     (__attribute__((address_space(3))) void*)l, 16, 0, 0);
}

// ---------------- W [1024][1024] f32 -> W^T [1024][1024] bf16 ----------------
__global__ __launch_bounds__(256) void tcast(const float* __restrict__ W, ushort* __restrict__ Wt) {
    __shared__ float tile[32][33];
    const int tx = threadIdx.x & 31, ty = threadIdx.x >> 5;   // ty 0..7
    const int n0 = blockIdx.x * 32, k0 = blockIdx.y * 32;
    #pragma unroll
    for (int i = 0; i < 4; i++)
        tile[ty + i*8][tx] = W[(size_t)(k0 + ty + i*8)*CC + n0 + tx];
    __syncthreads();
    #pragma unroll
    for (int i = 0; i < 4; i++)
        Wt[(size_t)(n0 + ty + i*8)*CC + k0 + tx] = f2bf(tile[tx][ty + i*8]);
}

// ---------------- fp32 -> bf16 elementwise ----------------
__global__ __launch_bounds__(256) void castx(const float* __restrict__ in, ushort* __restrict__ out) {
    int i = blockIdx.x * 256 + threadIdx.x;
    float4 v = ((const float4*)in)[i];
    ushort4 o; o.x = f2bf(v.x); o.y = f2bf(v.y); o.z = f2bf(v.z); o.w = f2bf(v.w);
    ((ushort4*)out)[i] = o;
}

// ---------------- gather KV rows (bf16, padded to 8704) ----------------
__global__ __launch_bounds__(256) void gather_kv(const float* __restrict__ x, const float* __restrict__ ht,
        const float* __restrict__ ha, const float* __restrict__ p, ushort* __restrict__ kvb) {
    int idx = blockIdx.x * 256 + threadIdx.x;   // one float4 slot
    int col4 = idx & 255;
    int row  = idx >> 8;                         // 0..8703
    ushort4 o;
    if (row < BB*KTOT) {
        int b = row / KTOT, j = row - b * KTOT;
        const float* src;
        if (j < 2048)      src = x  + ((size_t)b*TT + j)*CC;
        else if (j < 2112) src = ht + ((size_t)b*64 + (j-2048))*CC;
        else if (j < 2128) src = ha + ((size_t)b*16 + (j-2112))*CC;
        else               src = p  + ((size_t)b*32 + (j-2128))*CC;
        float4 v = ((const float4*)src)[col4];
        o.x = f2bf(v.x); o.y = f2bf(v.y); o.z = f2bf(v.z); o.w = f2bf(v.w);
    } else {
        o.x = 0; o.y = 0; o.z = 0; o.w = 0;
    }
    ((ushort4*)kvb)[idx] = o;
}

// ---------------- bf16 MFMA GEMM: C[M,1024] = A @ Bt^T + bias ----------------
// A bf16 [M][1024]; Bt bf16 [1024][1024] = W^T (rows = output cols, k-contiguous)
// EPI: 0 = none, 1 = +res (fp32), 2 = relu. Output fp32.
template<int EPI>
__global__ __launch_bounds__(256) void gemm_mfma(const ushort* __restrict__ A, const ushort* __restrict__ Bt,
        const float* __restrict__ bias, const float* __restrict__ res, float* __restrict__ C) {
    __shared__ ushort As[128*32];
    __shared__ ushort Bs[128*32];
    const int t = threadIdx.x;
    const int w = t >> 6, lane = t & 63;
    const int wr = w >> 1, wc = w & 1;
    const int row0 = blockIdx.y * 128, col0 = blockIdx.x * 128;
    const int lr = lane & 15, ls = lane >> 4;
    f32x4 acc[4][4] = {};
    for (int k0 = 0; k0 < CC; k0 += 32) {
        #pragma unroll
        for (int u = 0; u < 2; u++) {
            int i = u*256 + t;
            int r = i >> 2, pp = i & 3;
            int s = pp ^ ((r >> 1) & 3);            // inverse-swizzled global source
            const size_t goffA = (size_t)(row0 + r)*CC + k0 + s*8;
            const size_t goffB = (size_t)(col0 + r)*CC + k0 + s*8;
            async16(A  + goffA, &As[(u*256 + w*64)*8]);
            async16(Bt + goffB, &Bs[(u*256 + w*64)*8]);
        }
        __syncthreads();   // drains vmcnt: staged data visible
        bf16x8 af[4], bg[4];
        #pragma unroll
        for (int mi = 0; mi < 4; mi++) {
            int row = wr*64 + mi*16 + lr;
            af[mi] = *(const bf16x8*)&As[row*32 + (ls ^ ((row>>1)&3))*8];
        }
        #pragma unroll
        for (int ni = 0; ni < 4; ni++) {
            int row = wc*64 + ni*16 + lr;
            bg[ni] = *(const bf16x8*)&Bs[row*32 + (ls ^ ((row>>1)&3))*8];
        }
        #pragma unroll
        for (int mi = 0; mi < 4; mi++)
            #pragma unroll
            for (int ni = 0; ni < 4; ni++)
                acc[mi][ni] = __builtin_amdgcn_mfma_f32_16x16x32_bf16(af[mi], bg[ni], acc[mi][ni], 0, 0, 0);
        __syncthreads();   // compute done before next stage overwrites
    }
    #pragma unroll
    for (int ni = 0; ni < 4; ni++) {
        const int col = col0 + wc*64 + ni*16 + lr;
        const float bcol = bias[col];
        #pragma unroll
        for (int mi = 0; mi < 4; mi++) {
            f32x4 v = acc[mi][ni];
            #pragma unroll
            for (int q = 0; q < 4; q++) {
                int row = row0 + wr*64 + mi*16 + ls*4 + q;
                float o = v[q] + bcol;
                if (EPI == 1) o += res[(size_t)row*CC + col];
                if (EPI == 2) o = fmaxf(o, 0.f);
                C[(size_t)row*CC + col] = o;
            }
        }
    }
}

// ---------------- flash attention, fp32, QB=64 KB=32, bf16 out ----------------
__global__ __launch_bounds__(256) void attn_kernel(const float* __restrict__ Q, const float* __restrict__ Kg,
        const float* __restrict__ Vg, const float* __restrict__ gate, ushort* __restrict__ AO) {
    __shared__ float q_s[64][132];
    __shared__ float k_s[32][132];
    __shared__ float v_s[32][132];   // XOR bank-permuted columns
    __shared__ float s_s[64][36];
    const int qt = blockIdx.x, h = blockIdx.y, b = blockIdx.z;
    const int t = threadIdx.x;
    const int r = t >> 2, c = t & 3;         // row 0..63, col-group (cols c*32..c*32+31)
    const int q0 = qt * 64;
    const float ratio = tanhf(gate[0]);
    const float scl = 0.088388347648318447f; // 1/sqrt(128)
    #pragma unroll
    for (int u = 0; u < 8; u++) {
        int f = t + u*256;
        int rr = f >> 5, c4 = f & 31;
        *(float4*)&q_s[rr][c4*4] =
            *(const float4*)(Q + ((size_t)(b*TT + q0 + rr))*CC + h*DD + c4*4);
    }
    float o[32] = {};
    float m = -__builtin_inff(), l = 0.f;
    const size_t kvbase = (size_t)b * KTOT;
    for (int kt = 0; kt < 68; kt++) {
        const int j0 = kt * 32;
        const int nk = (KTOT - j0 < 32) ? (KTOT - j0) : 32;
        __syncthreads();   // protect k_s/v_s from previous iteration's readers
        #pragma unroll
        for (int u = 0; u < 4; u++) {
            int f = t + u*256;
            int rr = f >> 5, c4 = f & 31;
            if (rr < nk) {
                *(float4*)&k_s[rr][c4*4] =
                    *(const float4*)(Kg + (kvbase + j0 + rr)*CC + h*DD + c4*4);
                int d4 = c4*4;
                int phys = d4 ^ ((((unsigned)d4 >> 5) & 3) << 2);
                *(float4*)&v_s[rr][phys] =
                    *(const float4*)(Vg + (kvbase + j0 + rr)*CC + h*DD + c4*4);
            }
        }
        __syncthreads();
        // ---- scores: this thread handles keys jj = c + 4*ji ----
        float sacc[8] = {};
        #pragma unroll
        for (int d4 = 0; d4 < DD; d4 += 4) {
            float4 qv = *(const float4*)&q_s[r][d4];
            #pragma unroll
            for (int ji = 0; ji < 8; ji++) {
                const int jj = c + ji*4;
                float4 kv = *(const float4*)&k_s[jj][d4];
                sacc[ji] = fmaf(qv.x, kv.x, sacc[ji]);
                sacc[ji] = fmaf(qv.y, kv.y, sacc[ji]);
                sacc[ji] = fmaf(qv.z, kv.z, sacc[ji]);
                sacc[ji] = fmaf(qv.w, kv.w, sacc[ji]);
            }
        }
        #pragma unroll
        for (int ji = 0; ji < 8; ji++) {
            const int jj = c + ji*4;
            const int jg = j0 + jj;
            float s;
            if (jg < KTOT) {
                float gm = (jg >= GATE0) ? ratio : 1.0f;
                s = sacc[ji] * gm * scl;
            } else {
                s = -__builtin_inff();
            }
            s_s[r][jj] = s;
        }
        // ---- online softmax (row r owned by lanes 4r..4r+3, same wave) ----
        float tmax = m;
        #pragma unroll
        for (int j4 = 0; j4 < 32; j4 += 4) {
            float4 sv = *(const float4*)&s_s[r][j4];
            tmax = fmaxf(tmax, fmaxf(fmaxf(sv.x, sv.y), fmaxf(sv.z, sv.w)));
        }
        const float rescale = __expf(m - tmax);
        m = tmax;
        l *= rescale;
        #pragma unroll
        for (int i = 0; i < 32; i++) o[i] *= rescale;
        float lsum = 0.f;
        #pragma unroll
        for (int jq = 0; jq < 2; jq++) {
            float4 sv = *(const float4*)&s_s[r][c*8 + jq*4];
            float4 pv;
            pv.x = __expf(sv.x - m);
            pv.y = __expf(sv.y - m);
            pv.z = __expf(sv.z - m);
            pv.w = __expf(sv.w - m);
            lsum += pv.x + pv.y + pv.z + pv.w;
            *(float4*)&s_s[r][c*8 + jq*4] = pv;
        }
        lsum += __shfl_xor(lsum, 1);
        lsum += __shfl_xor(lsum, 2);
        l += lsum;
        // ---- accumulate O += P @ V ----
        #pragma unroll
        for (int j = 0; j < 32; j++) {
            const float pj = s_s[r][j];
            #pragma unroll
            for (int ii = 0; ii < 8; ii++) {
                const int d4 = c*32 + ii*4;
                const int phys = d4 ^ (c << 2);
                float4 vv = *(const float4*)&v_s[j][phys];
                o[ii*4+0] = fmaf(pj, vv.x, o[ii*4+0]);
                o[ii*4+1] = fmaf(pj, vv.y, o[ii*4+1]);
                o[ii*4+2] = fmaf(pj, vv.z, o[ii*4+2]);
                o[ii*4+3] = fmaf(pj, vv.w, o[ii*4+3]);
            }
        }
    }
    const float invl = 1.0f / l;
    #pragma unroll
    for (int ii = 0; ii < 8; ii++) {
        ushort4 ov;
        ov.x = f2bf(o[ii*4+0] * invl);
        ov.y = f2bf(o[ii*4+1] * invl);
        ov.z = f2bf(o[ii*4+2] * invl);
        ov.w = f2bf(o[ii*4+3] * invl);
        *(ushort4*)(AO + ((size_t)(b*TT + q0 + r))*CC + h*DD + c*32 + ii*4) = ov;
    }
}

// ---------------- LayerNorm over last dim (1024), bf16 out ----------------
__global__ __launch_bounds__(256) void ln_kernel(const float* __restrict__ Y, const float* __restrict__ g,
        const float* __restrict__ bb, ushort* __restrict__ Out) {
    const int row = blockIdx.x;
    const int t = threadIdx.x;
    float4 v = ((const float4*)(Y + (size_t)row*CC))[t];
    float s  = v.x + v.y + v.z + v.w;
    float sq = v.x*v.x + v.y*v.y + v.z*v.z + v.w*v.w;
    #pragma unroll
    for (int off = 32; off >= 1; off >>= 1) {
        s  += __shfl_xor(s, off);
        sq += __shfl_xor(sq, off);
    }
    __shared__ float ssum[4], ssq[4];
    const int w = t >> 6;
    if ((t & 63) == 0) { ssum[w] = s; ssq[w] = sq; }
    __syncthreads();
    s  = ssum[0] + ssum[1] + ssum[2] + ssum[3];
    sq = ssq[0]  + ssq[1]  + ssq[2]  + ssq[3];
    const float mu  = s * (1.f/1024.f);
    const float var = sq * (1.f/1024.f) - mu*mu;
    const float inv = rsqrtf(var + 1e-5f);
    float4 g4 = ((const float4*)g)[t];
    float4 b4 = ((const float4*)bb)[t];
    ushort4 o;
    o.x = f2bf((v.x - mu)*inv*g4.x + b4.x);
    o.y = f2bf((v.y - mu)*inv*g4.y + b4.y);
    o.z = f2bf((v.z - mu)*inv*g4.z + b4.z);
    o.w = f2bf((v.w - mu)*inv*g4.w + b4.w);
    ((ushort4*)(Out + (size_t)row*CC))[t] = o;
}

extern "C" void kernel_launch(void* const* d_in, const int* in_sizes, int n_in,
                              void* d_out, int out_size, void* d_ws, size_t ws_size,
                              hipStream_t stream) {
    const float* x    = (const float*)d_in[0];
    const float* h_t  = (const float*)d_in[1];
    const float* h_a  = (const float*)d_in[2];
    const float* p    = (const float*)d_in[3];
    const float* Wq   = (const float*)d_in[4];
    const float* bq   = (const float*)d_in[5];
    const float* Wk   = (const float*)d_in[6];
    const float* bk   = (const float*)d_in[7];
    const float* Wv   = (const float*)d_in[8];
    const float* bv   = (const float*)d_in[9];
    const float* Wo   = (const float*)d_in[10];
    const float* bo   = (const float*)d_in[11];
    const float* ln_g = (const float*)d_in[12];
    const float* ln_b = (const float*)d_in[13];
    const float* Wf   = (const float*)d_in[14];
    const float* bf   = (const float*)d_in[15];
    const float* gate = (const float*)d_in[16];
    float* out = (float*)d_out;

    // workspace layout (bytes all 16B-aligned by construction)
    ushort* wqT = (ushort*)d_ws;                       // 1M ushort each
    ushort* wkT = wqT + (size_t)CC*CC;
    ushort* wvT = wkT + (size_t)CC*CC;
    ushort* woT = wvT + (size_t)CC*CC;
    ushort* wfT = woT + (size_t)CC*CC;
    ushort* xb  = wfT + (size_t)CC*CC;                 // 8M ushort
    ushort* kvb = xb  + (size_t)MQ*CC;                 // 8704*1024 ushort
    float*  Qf  = (float*)(kvb + (size_t)MKVP*CC);     // 8M f32
    float*  Kf  = Qf + (size_t)MQ*CC;                  // 8704*1024 f32
    float*  Vf  = Kf + (size_t)MKVP*CC;                // 8704*1024 f32
    ushort* AOb = xb;                                  // alias: xb dead after Q GEMM
    float*  Y   = Qf;                                  // alias: Qf dead after attention
    ushort* YNb = kvb;                                 // alias: kvb dead after K/V GEMMs

    tcast<<<dim3(32,32), 256, 0, stream>>>(Wq, wqT);
    tcast<<<dim3(32,32), 256, 0, stream>>>(Wk, wkT);
    tcast<<<dim3(32,32), 256, 0, stream>>>(Wv, wvT);
    tcast<<<dim3(32,32), 256, 0, stream>>>(Wo, woT);
    tcast<<<dim3(32,32), 256, 0, stream>>>(Wf, wfT);
    castx<<<MQ*CC/4/256, 256, 0, stream>>>(x, xb);
    gather_kv<<<MKVP, 256, 0, stream>>>(x, h_t, h_a, p, kvb);

    gemm_mfma<0><<<dim3(8, MQ/128),   256, 0, stream>>>(xb,  wqT, bq, nullptr, Qf);
    gemm_mfma<0><<<dim3(8, MKVP/128), 256, 0, stream>>>(kvb, wkT, bk, nullptr, Kf);
    gemm_mfma<0><<<dim3(8, MKVP/128), 256, 0, stream>>>(kvb, wvT, bv, nullptr, Vf);
    attn_kernel<<<dim3(TT/64, HH, BB), 256, 0, stream>>>(Qf, Kf, Vf, gate, AOb);
    gemm_mfma<1><<<dim3(8, MQ/128),   256, 0, stream>>>(AOb, woT, bo, x, Y);
    ln_kernel<<<MQ, 256, 0, stream>>>(Y, ln_g, ln_b, YNb);
    gemm_mfma<2><<<dim3(8, MQ/128),   256, 0, stream>>>(YNb, wfT, bf, nullptr, out);
}

// Round 3
// 328.342 us; speedup vs baseline: 10.3004x; 7.4291x over previous
//
#include <hip/hip_runtime.h>

#define BB 4
#define TT 2048
#define CC 1024
#define HH 8
#define DD 128
#define KTOT 2160
#define GATE0 2112
#define KP 2176            /* keys padded per batch: 34*64 */
#define NT 34              /* KV tiles per (b,h) */
#define MQ (BB*TT)
#define MKVP (BB*KP)       /* 8704 */

typedef __attribute__((ext_vector_type(4)))  float f32x4;
typedef __attribute__((ext_vector_type(16))) float f32x16;
typedef __attribute__((ext_vector_type(8)))  short bf16x8;

union PU { unsigned u[4]; bf16x8 v; };

__device__ __forceinline__ unsigned short f2bf(float f) {
    unsigned u = __float_as_uint(f);
    unsigned r = u + 0x7FFFu + ((u >> 16) & 1u);
    return (unsigned short)(r >> 16);
}
__device__ __forceinline__ unsigned pk2(float a, float b) {
    return (unsigned)f2bf(a) | ((unsigned)f2bf(b) << 16);
}
__device__ __forceinline__ void async16(const ushort* g, ushort* l) {
    __builtin_amdgcn_global_load_lds((const __attribute__((address_space(1))) void*)g,
                                     (__attribute__((address_space(3))) void*)l, 16, 0, 0);
}

// ---------------- W [1024][1024] f32 -> W^T [1024][1024] bf16 ----------------
__global__ __launch_bounds__(256) void tcast(const float* __restrict__ W, ushort* __restrict__ Wt) {
    __shared__ float tile[32][33];
    const int tx = threadIdx.x & 31, ty = threadIdx.x >> 5;
    const int n0 = blockIdx.x * 32, k0 = blockIdx.y * 32;
    #pragma unroll
    for (int i = 0; i < 4; i++)
        tile[ty + i*8][tx] = W[(size_t)(k0 + ty + i*8)*CC + n0 + tx];
    __syncthreads();
    #pragma unroll
    for (int i = 0; i < 4; i++)
        Wt[(size_t)(n0 + ty + i*8)*CC + k0 + tx] = f2bf(tile[tx][ty + i*8]);
}

// ---------------- fp32 -> bf16 elementwise ----------------
__global__ __launch_bounds__(256) void castx(const float* __restrict__ in, ushort* __restrict__ out) {
    int i = blockIdx.x * 256 + threadIdx.x;
    float4 v = ((const float4*)in)[i];
    ushort4 o; o.x = f2bf(v.x); o.y = f2bf(v.y); o.z = f2bf(v.z); o.w = f2bf(v.w);
    ((ushort4*)out)[i] = o;
}

// ---------------- gather KV rows (bf16, per-batch padded to 2176) ----------------
__global__ __launch_bounds__(256) void gather_kv(const float* __restrict__ x, const float* __restrict__ ht,
        const float* __restrict__ ha, const float* __restrict__ p, ushort* __restrict__ kvb) {
    int idx = blockIdx.x * 256 + threadIdx.x;   // one 4-elem slot
    int col4 = idx & 255;
    int row  = idx >> 8;                         // 0..8703
    int b = row / KP, j = row - b * KP;
    ushort4 o;
    if (j < KTOT) {
        const float* src;
        if (j < 2048)      src = x  + ((size_t)b*TT + j)*CC;
        else if (j < 2112) src = ht + ((size_t)b*64 + (j-2048))*CC;
        else if (j < 2128) src = ha + ((size_t)b*16 + (j-2112))*CC;
        else               src = p  + ((size_t)b*32 + (j-2128))*CC;
        float4 v = ((const float4*)src)[col4];
        o.x = f2bf(v.x); o.y = f2bf(v.y); o.z = f2bf(v.z); o.w = f2bf(v.w);
    } else {
        o.x = 0; o.y = 0; o.z = 0; o.w = 0;
    }
    ((ushort4*)kvb)[idx] = o;
}

// ---------------- bf16 MFMA GEMM: C[M,1024] = A @ Wt^T + bias ----------------
// EPI: 0 none, 1 +res(f32), 2 relu.  OUT: 0 f32, 1 bf16 row-major, 2 bf16 head-transposed (Vt)
template<int EPI, int OUT>
__global__ __launch_bounds__(256) void gemm_mfma(const ushort* __restrict__ A, const ushort* __restrict__ Bt,
        const float* __restrict__ bias, const float* __restrict__ res, void* __restrict__ Cv) {
    __shared__ ushort As[128*32];
    __shared__ ushort Bs[128*32];
    const int t = threadIdx.x;
    const int w = t >> 6, lane = t & 63;
    const int wr = w >> 1, wc = w & 1;
    const int row0 = blockIdx.y * 128, col0 = blockIdx.x * 128;
    const int lr = lane & 15, ls = lane >> 4;
    f32x4 acc[4][4] = {};
    for (int k0 = 0; k0 < CC; k0 += 32) {
        #pragma unroll
        for (int u = 0; u < 2; u++) {
            int i = u*256 + t;
            int r = i >> 2, pp = i & 3;
            int s = pp ^ ((r >> 1) & 3);
            async16(A  + (size_t)(row0 + r)*CC + k0 + s*8, &As[(u*256 + w*64)*8]);
            async16(Bt + (size_t)(col0 + r)*CC + k0 + s*8, &Bs[(u*256 + w*64)*8]);
        }
        __syncthreads();
        bf16x8 af[4], bg[4];
        #pragma unroll
        for (int mi = 0; mi < 4; mi++) {
            int row = wr*64 + mi*16 + lr;
            af[mi] = *(const bf16x8*)&As[row*32 + (ls ^ ((row>>1)&3))*8];
        }
        #pragma unroll
        for (int ni = 0; ni < 4; ni++) {
            int row = wc*64 + ni*16 + lr;
            bg[ni] = *(const bf16x8*)&Bs[row*32 + (ls ^ ((row>>1)&3))*8];
        }
        #pragma unroll
        for (int mi = 0; mi < 4; mi++)
            #pragma unroll
            for (int ni = 0; ni < 4; ni++)
                acc[mi][ni] = __builtin_amdgcn_mfma_f32_16x16x32_bf16(af[mi], bg[ni], acc[mi][ni], 0, 0, 0);
        __syncthreads();
    }
    #pragma unroll
    for (int ni = 0; ni < 4; ni++) {
        const int col = col0 + wc*64 + ni*16 + lr;
        const float bcol = bias[col];
        #pragma unroll
        for (int mi = 0; mi < 4; mi++) {
            f32x4 v = acc[mi][ni];
            #pragma unroll
            for (int q = 0; q < 4; q++) {
                int row = row0 + wr*64 + mi*16 + ls*4 + q;
                float o = v[q] + bcol;
                if (EPI == 1) o += res[(size_t)row*CC + col];
                if (EPI == 2) o = fmaxf(o, 0.f);
                if (OUT == 0) {
                    ((float*)Cv)[(size_t)row*CC + col] = o;
                } else if (OUT == 1) {
                    ((ushort*)Cv)[(size_t)row*CC + col] = f2bf(o);
                } else {
                    int b = row / KP, j = row - b * KP;
                    int hh = col >> 7, dout = col & 127;
                    ((ushort*)Cv)[((size_t)((b*HH + hh)*DD + dout))*KP + j] = f2bf(o);
                }
            }
        }
    }
}

// ---------------- MFMA flash attention: 4 waves x 32 q-rows, KV tiles of 64 ----------------
__global__ __launch_bounds__(256, 2) void attn_mfma(const ushort* __restrict__ Qb,
        const ushort* __restrict__ Kb, const ushort* __restrict__ Vtb,
        const float* __restrict__ gate, ushort* __restrict__ AO) {
    __shared__ ushort s_k[2][64*128];   // K tile [64 keys][128 d], rows 256B, XOR-swizzled
    __shared__ ushort s_v[2][128*64];   // Vt tile [128 d][64 j], rows 128B, XOR-swizzled
    __shared__ float  l_s[4][32];
    const int t = threadIdx.x;
    const int w = t >> 6, lane = t & 63;
    const int ql = lane & 31, H = lane >> 5;
    const int qb0 = blockIdx.x * 128;
    const int h = blockIdx.y, b = blockIdx.z;
    const float ratio = tanhf(gate[0]);
    const float scl = 0.088388347648318447f;   // 1/sqrt(128)

    // ---- stage Q tile [128 q][128 d] into s_k[0]|s_v[0], swizzled ----
    #pragma unroll
    for (int u = 0; u < 8; u++) {
        int s16 = u*256 + t;                  // 16B-slot index 0..2047
        int row = s16 >> 4, slot = s16 & 15;
        int ss = slot ^ (row & 7);
        const ushort* src = Qb + (size_t)(b*TT + qb0 + row)*CC + h*DD + ss*8;
        ushort* dst = (s16 < 1024) ? &s_k[0][s16*8] : &s_v[0][(s16 - 1024)*8];
        async16(src, dst);
    }
    asm volatile("s_waitcnt vmcnt(0)" ::: "memory");
    __builtin_amdgcn_s_barrier();
    bf16x8 qf[8];
    {
        int row = w*32 + ql;
        int swz = (row & 7) << 4;
        #pragma unroll
        for (int ds = 0; ds < 8; ds++) {
            int off = (ds*32 + H*16) ^ swz;
            const ushort* base = (row < 64) ? &s_k[0][row*128 + off/2]
                                            : &s_v[0][(row-64)*128 + off/2];
            qf[ds] = *(const bf16x8*)base;
        }
    }
    asm volatile("s_waitcnt lgkmcnt(0)" ::: "memory");
    __builtin_amdgcn_s_barrier();

    f32x16 oacc[4] = {};
    float m = -__builtin_inff(), l = 0.f;

    // prologue: stage tile 0 into buf 0
    {
        #pragma unroll
        for (int u = 0; u < 4; u++) {
            int s16 = u*256 + t;
            int row = s16 >> 4, slot = s16 & 15;
            int ss = slot ^ (row & 7);
            async16(Kb + (size_t)(b*KP + row)*CC + h*DD + ss*8, &s_k[0][s16*8]);
        }
        #pragma unroll
        for (int u = 0; u < 4; u++) {
            int s16 = u*256 + t;
            int row = s16 >> 3, slot = s16 & 7;
            int ss = slot ^ (row & 7);
            async16(Vtb + ((size_t)((b*HH + h)*DD + row))*KP + ss*8, &s_v[0][s16*8]);
        }
    }

    for (int tile = 0; tile < NT; tile++) {
        const int cur = tile & 1;
        if (tile + 1 < NT) {
            const int j0n = (tile+1) * 64;
            #pragma unroll
            for (int u = 0; u < 4; u++) {
                int s16 = u*256 + t;
                int row = s16 >> 4, slot = s16 & 15;
                int ss = slot ^ (row & 7);
                async16(Kb + (size_t)(b*KP + j0n + row)*CC + h*DD + ss*8, &s_k[cur^1][s16*8]);
            }
            #pragma unroll
            for (int u = 0; u < 4; u++) {
                int s16 = u*256 + t;
                int row = s16 >> 3, slot = s16 & 7;
                int ss = slot ^ (row & 7);
                async16(Vtb + ((size_t)((b*HH + h)*DD + row))*KP + j0n + ss*8, &s_v[cur^1][s16*8]);
            }
            asm volatile("s_waitcnt vmcnt(8)" ::: "memory");
        } else {
            asm volatile("s_waitcnt vmcnt(0)" ::: "memory");
        }
        __builtin_amdgcn_s_barrier();

        const ushort* ks = s_k[cur];
        const ushort* vs = s_v[cur];
        const int j0 = tile * 64;

        // ---- ST = K . Q^T : rows = keys (crow), cols = q (ql) ----
        f32x16 st0 = {}, st1 = {};
        {
            int swz = (ql & 7) << 4;   // (32+ql)&7 == ql&7
            #pragma unroll
            for (int ds = 0; ds < 8; ds++) {
                int off = (ds*32 + H*16) ^ swz;
                bf16x8 k0 = *(const bf16x8*)&ks[ ql      *128 + off/2];
                bf16x8 k1 = *(const bf16x8*)&ks[(32+ql)*128 + off/2];
                st0 = __builtin_amdgcn_mfma_f32_32x32x16_bf16(k0, qf[ds], st0, 0, 0, 0);
                st1 = __builtin_amdgcn_mfma_f32_32x32x16_bf16(k1, qf[ds], st1, 0, 0, 0);
            }
        }

        // ---- scale / gate / mask ----
        float p0[16], p1[16];
        if (j0 == 2112) {
            #pragma unroll
            for (int r = 0; r < 16; r++) {
                int cr = (r&3) + 8*(r>>2) + 4*H;
                p0[r] = st0[r] * scl * ratio;                               // keys 2112..2143: gated
                p1[r] = (2144 + cr < KTOT) ? st1[r] * scl * ratio
                                           : -__builtin_inff();            // pad keys >= 2160
            }
        } else {
            #pragma unroll
            for (int r = 0; r < 16; r++) { p0[r] = st0[r]*scl; p1[r] = st1[r]*scl; }
        }

        // ---- online softmax (per-lane row; halves combined via shfl_xor 32) ----
        float tm = -__builtin_inff();
        #pragma unroll
        for (int r = 0; r < 16; r++) tm = fmaxf(tm, fmaxf(p0[r], p1[r]));
        tm = fmaxf(tm, __shfl_xor(tm, 32));
        if (!__all(tm <= m + 8.f)) {           // defer-max (T13)
            float nm = fmaxf(m, tm);
            float rs = __expf(m - nm);
            m = nm;
            l *= rs;
            #pragma unroll
            for (int dt = 0; dt < 4; dt++)
                #pragma unroll
                for (int r = 0; r < 16; r++) oacc[dt][r] *= rs;
        }
        float lsum = 0.f;
        #pragma unroll
        for (int r = 0; r < 16; r++) {
            p0[r] = __expf(p0[r] - m);
            p1[r] = __expf(p1[r] - m);
            lsum += p0[r] + p1[r];
        }
        lsum += __shfl_xor(lsum, 32);
        l += lsum;

        // ---- PV: assemble P A-fragments in-register, multiply Vt B-fragments ----
        #pragma unroll
        for (int jt = 0; jt < 4; jt++) {
            const float* ps = (jt < 2) ? p0 : p1;
            const int ib = (jt & 1) * 8;
            unsigned PA0 = pk2(ps[ib+0], ps[ib+1]);
            unsigned PA1 = pk2(ps[ib+2], ps[ib+3]);
            unsigned PB0 = pk2(ps[ib+4], ps[ib+5]);
            unsigned PB1 = pk2(ps[ib+6], ps[ib+7]);
            unsigned send0 = H ? PA0 : PB0;
            unsigned send1 = H ? PA1 : PB1;
            unsigned recv0 = (unsigned)__shfl_xor((int)send0, 32);
            unsigned recv1 = (unsigned)__shfl_xor((int)send1, 32);
            PU pu;
            pu.u[0] = H ? recv0 : PA0;
            pu.u[1] = H ? recv1 : PA1;
            pu.u[2] = H ? PB0  : recv0;
            pu.u[3] = H ? PB1  : recv1;
            #pragma unroll
            for (int dt = 0; dt < 4; dt++) {
                int row = dt*32 + ql;
                int off = (jt*32 + H*16) ^ ((row & 7) << 4);
                bf16x8 vf = *(const bf16x8*)&vs[row*64 + off/2];
                oacc[dt] = __builtin_amdgcn_mfma_f32_32x32x16_bf16(pu.v, vf, oacc[dt], 0, 0, 0);
            }
        }
        __builtin_amdgcn_s_barrier();
    }

    // ---- epilogue: divide by l, store bf16 ----
    l_s[w][ql] = 1.0f / l;
    __syncthreads();
    float il[16];
    #pragma unroll
    for (int r = 0; r < 16; r++) il[r] = l_s[w][(r&3) + 8*(r>>2) + 4*H];
    #pragma unroll
    for (int dt = 0; dt < 4; dt++)
        #pragma unroll
        for (int r = 0; r < 16; r++) {
            int cr = (r&3) + 8*(r>>2) + 4*H;
            size_t row = (size_t)(b*TT + qb0 + w*32 + cr);
            AO[row*CC + h*DD + dt*32 + ql] = f2bf(oacc[dt][r] * il[r]);
        }
}

// ---------------- LayerNorm over last dim (1024), bf16 out ----------------
__global__ __launch_bounds__(256) void ln_kernel(const float* __restrict__ Y, const float* __restrict__ g,
        const float* __restrict__ bb, ushort* __restrict__ Out) {
    const int row = blockIdx.x;
    const int t = threadIdx.x;
    float4 v = ((const float4*)(Y + (size_t)row*CC))[t];
    float s  = v.x + v.y + v.z + v.w;
    float sq = v.x*v.x + v.y*v.y + v.z*v.z + v.w*v.w;
    #pragma unroll
    for (int off = 32; off >= 1; off >>= 1) {
        s  += __shfl_xor(s, off);
        sq += __shfl_xor(sq, off);
    }
    __shared__ float ssum[4], ssq[4];
    const int w = t >> 6;
    if ((t & 63) == 0) { ssum[w] = s; ssq[w] = sq; }
    __syncthreads();
    s  = ssum[0] + ssum[1] + ssum[2] + ssum[3];
    sq = ssq[0]  + ssq[1]  + ssq[2]  + ssq[3];
    const float mu  = s * (1.f/1024.f);
    const float var = sq * (1.f/1024.f) - mu*mu;
    const float inv = rsqrtf(var + 1e-5f);
    float4 g4 = ((const float4*)g)[t];
    float4 b4 = ((const float4*)bb)[t];
    ushort4 o;
    o.x = f2bf((v.x - mu)*inv*g4.x + b4.x);
    o.y = f2bf((v.y - mu)*inv*g4.y + b4.y);
    o.z = f2bf((v.z - mu)*inv*g4.z + b4.z);
    o.w = f2bf((v.w - mu)*inv*g4.w + b4.w);
    ((ushort4*)(Out + (size_t)row*CC))[t] = o;
}

extern "C" void kernel_launch(void* const* d_in, const int* in_sizes, int n_in,
                              void* d_out, int out_size, void* d_ws, size_t ws_size,
                              hipStream_t stream) {
    const float* x    = (const float*)d_in[0];
    const float* h_t  = (const float*)d_in[1];
    const float* h_a  = (const float*)d_in[2];
    const float* p    = (const float*)d_in[3];
    const float* Wq   = (const float*)d_in[4];
    const float* bq   = (const float*)d_in[5];
    const float* Wk   = (const float*)d_in[6];
    const float* bk   = (const float*)d_in[7];
    const float* Wv   = (const float*)d_in[8];
    const float* bv   = (const float*)d_in[9];
    const float* Wo   = (const float*)d_in[10];
    const float* bo   = (const float*)d_in[11];
    const float* ln_g = (const float*)d_in[12];
    const float* ln_b = (const float*)d_in[13];
    const float* Wf   = (const float*)d_in[14];
    const float* bf   = (const float*)d_in[15];
    const float* gate = (const float*)d_in[16];
    float* out = (float*)d_out;

    ushort* wqT = (ushort*)d_ws;
    ushort* wkT = wqT + (size_t)CC*CC;
    ushort* wvT = wkT + (size_t)CC*CC;
    ushort* woT = wvT + (size_t)CC*CC;
    ushort* wfT = woT + (size_t)CC*CC;
    ushort* xb  = wfT + (size_t)CC*CC;                 // [8192][1024] bf16
    ushort* kvb = xb  + (size_t)MQ*CC;                 // [8704][1024] bf16
    ushort* Qb  = kvb + (size_t)MKVP*CC;               // [8192][1024] bf16
    ushort* Kb  = Qb  + (size_t)MQ*CC;                 // [8704][1024] bf16
    ushort* Vtb = Kb  + (size_t)MKVP*CC;               // [B][H][128][2176] bf16
    ushort* AOb = xb;                                  // alias: xb dead after Q GEMM
    float*  Y   = (float*)Qb;                          // alias: Qb+Kb dead after attention
    ushort* YNb = kvb;                                 // alias: kvb dead after K/V GEMMs

    tcast<<<dim3(32,32), 256, 0, stream>>>(Wq, wqT);
    tcast<<<dim3(32,32), 256, 0, stream>>>(Wk, wkT);
    tcast<<<dim3(32,32), 256, 0, stream>>>(Wv, wvT);
    tcast<<<dim3(32,32), 256, 0, stream>>>(Wo, woT);
    tcast<<<dim3(32,32), 256, 0, stream>>>(Wf, wfT);
    castx<<<MQ*CC/4/256, 256, 0, stream>>>(x, xb);
    gather_kv<<<MKVP, 256, 0, stream>>>(x, h_t, h_a, p, kvb);

    gemm_mfma<0,1><<<dim3(8, MQ/128),   256, 0, stream>>>(xb,  wqT, bq, nullptr, Qb);
    gemm_mfma<0,1><<<dim3(8, MKVP/128), 256, 0, stream>>>(kvb, wkT, bk, nullptr, Kb);
    gemm_mfma<0,2><<<dim3(8, MKVP/128), 256, 0, stream>>>(kvb, wvT, bv, nullptr, Vtb);
    attn_mfma<<<dim3(TT/128, HH, BB), 256, 0, stream>>>(Qb, Kb, Vtb, gate, AOb);
    gemm_mfma<1,0><<<dim3(8, MQ/128),   256, 0, stream>>>(AOb, woT, bo, x, Y);
    ln_kernel<<<MQ, 256, 0, stream>>>(Y, ln_g, ln_b, YNb);
    gemm_mfma<2,0><<<dim3(8, MQ/128),   256, 0, stream>>>(YNb, wfT, bf, nullptr, (void*)out);
}